// Round 10
// baseline (240.913 us; speedup 1.0000x reference)
//
#include <hip/hip_runtime.h>
#include <hip/hip_fp16.h>

// LMKAN_2D: out(O=256,B=4096) = relu(W(256x128)@x(128x4096) + bias_l)
//           + w_lm * sum_p bilinear4(fp[i,j,:,p])
// K1 transpose: fp[i][j][o][p] f32 -> fpt[p][i][j][o] f16 (132 MiB). Per-p
//    slab = contiguous 2.1 MiB. Loads 1KB/wave; stores 2x512B segments.
// K2 gather (persistent, PHYSICAL-XCD-phased): 512 blocks x 256 thr.
//    pgroup = s_getreg(HW_REG_XCC_ID) — R9 lesson: bid&7 != physical XCD;
//    time-aligned phases landed in L3 (~3.7 TB/s scatter = 133us) but never
//    in the owning L2. Work claim: per-pgroup atomic tickets + steal
//    fallback (coverage guaranteed for ANY dispatch; deterministic output).
//    Per phase: stream-prefetch next slab (contiguous, full HBM rate),
//    gather from L2-resident current slab, RELAXED-only barrier (no
//    L2-invalidate — R8 lesson), bounded spin (timing-only).
// K3 linear: 128-block GEMM computes relu(Wx+b), folds 8 partials, writes out.

#define NB 4096
#define ND 128
#define NO 256
#define NP 64
#define NG 65
#define NPANEL 4225              // 65*65
#define PANEL 16384              // 256*64 elements per (i,j) src panel
#define SLAB_ELEMS ((size_t)NPANEL * NO)   // 1,081,600 halves = 2.06 MiB
#define SLAB_VEC4 135200                   // slab bytes / 16
#define FPT_ELEMS ((size_t)NP * NPANEL * NO)
#define FPT_BYTES (FPT_ELEMS * 2)
#define PART_FLOATS ((size_t)8 * NB * NO)  // 32 MiB
#define NBLK 512
#define BARS 64
// ctrl layout (u32): tickets[g] at g*64 (512 u32); phase cnt (g,ph) at
// 512 + (g*8+ph)*64 (4096 u32). Total 8192 u32 = 32 KB, reset by K1.
#define CTRL_U32 8192

typedef float f32x4 __attribute__((ext_vector_type(4)));
union Pack8 { __half h[8]; uint4 v; };

__device__ __forceinline__ int bsearch65(const float* B, float v) {
  int lo = 0, hi = 65;
  while (lo < hi) {
    int m = (lo + hi) >> 1;
    if (B[m] <= v) lo = m + 1; else hi = m;
  }
  int i = lo - 1;
  return i < 0 ? 0 : (i > 63 ? 63 : i);
}

__device__ __forceinline__ void borders_init(float* borders, int t) {
  if (t < 65) {
    float pk = fminf(fmaxf((float)t * (1.0f / 64.0f), 0.0078125f), 0.9921875f);
    borders[t] = 1.41421356237309515f * erfinvf(2.0f * pk - 1.0f);
  }
}

// RELAXED-only phase wait on one 256B counter line. Timing aid only:
// bounded spin (~10us cap), correctness never depends on it.
__device__ __forceinline__ void phase_wait(unsigned* cline) {
  __syncthreads();
  if (threadIdx.x == 0) {
    __hip_atomic_fetch_add(cline, 1u, __ATOMIC_RELAXED, __HIP_MEMORY_SCOPE_AGENT);
    for (int it = 0; it < 12; ++it) {
      if (__hip_atomic_load(cline, __ATOMIC_RELAXED,
                            __HIP_MEMORY_SCOPE_AGENT) >= BARS) break;
      __builtin_amdgcn_s_sleep(32);   // ~0.85us between polls
    }
  }
  __syncthreads();
}

// ---- K1: transpose fp[panel][o][p] f32 -> fpt[p][panel][o] f16 ----
__global__ __launch_bounds__(256) void lmkan_transpose4(
    const float* __restrict__ src, __half* __restrict__ dst,
    unsigned* __restrict__ ctrl) {
  const int panel = blockIdx.x;
  const int t = threadIdx.x;
  __shared__ __half lds[256 * 72];   // [o][72], p XOR-swizzled inside row

  if (panel == 0) {                  // reset tickets + phase counters
#pragma unroll
    for (int k = 0; k < 32; ++k) ctrl[t + 256 * k] = 0u;
  }

  const f32x4* s4 = reinterpret_cast<const f32x4*>(src + (size_t)panel * PANEL);
#pragma unroll
  for (int k = 0; k < 16; ++k) {
    int idx4 = t + 256 * k;          // 1KB contiguous per wave
    f32x4 v = __builtin_nontemporal_load(&s4[idx4]);  // read-once
    int o = idx4 >> 4;
    int p0 = (idx4 & 15) * 4;
    int p0s = p0 ^ (((o >> 3) & 15) << 2);
    union { __half2 h2[2]; uint2 u; } pk;
    pk.h2[0] = __floats2half2_rn(v[0], v[1]);
    pk.h2[1] = __floats2half2_rn(v[2], v[3]);
    *reinterpret_cast<uint2*>(&lds[o * 72 + p0s]) = pk.u;
  }
  __syncthreads();

  const int l = t & 63, w = t >> 6;
  const int o0 = (l & 31) * 8;
  const int swz = (l & 15) << 2;
#pragma unroll
  for (int ss = 0; ss < 8; ++ss) {
    int p = ss * 8 + w * 2 + (l >> 5);
    int prow = ((p & ~3) ^ swz) + (p & 3);
    Pack8 pk;
#pragma unroll
    for (int r = 0; r < 8; ++r) pk.h[r] = lds[(o0 + r) * 72 + prow];
    // dst row (p, panel): slab-contiguous layout
    *reinterpret_cast<uint4*>(dst + ((size_t)p * NPANEL + panel) * NO + o0) = pk.v;
  }
}

__device__ __forceinline__ void fma4h(float acc[4], float w, uint2 v) {
  __half2 h0 = *reinterpret_cast<__half2*>(&v.x);
  __half2 h1 = *reinterpret_cast<__half2*>(&v.y);
  float2 f0 = __half22float2(h0);
  float2 f1 = __half22float2(h1);
  acc[0] = fmaf(w, f0.x, acc[0]);
  acc[1] = fmaf(w, f0.y, acc[1]);
  acc[2] = fmaf(w, f1.x, acc[2]);
  acc[3] = fmaf(w, f1.y, acc[3]);
}

// stream-prefetch 1/64th of a slab into this XCD's L2 (coalesced team read)
__device__ __forceinline__ void slab_prefetch(const __half* slabp, int c, int t) {
  const f32x4* pf = reinterpret_cast<const f32x4*>(slabp);
  const int tid = c * 256 + t;       // team-wide id 0..16383
  float s = 0.0f;
#pragma unroll
  for (int k = 0; k < 9; ++k) {
    int i = tid + 16384 * k;
    if (i < SLAB_VEC4) {
      f32x4 v = pf[i];
      s += v[0] + v[3];
    }
  }
  asm volatile("" :: "v"(s));        // keep loads alive (rule #17)
}

// ---- K2: physical-XCD-phased gather -> partials ----
__global__ __launch_bounds__(256, 2) void lmkan_gather10(
    const float* __restrict__ x, const float* __restrict__ scale,
    const float* __restrict__ biasp, const __half* __restrict__ fpt,
    float* __restrict__ part, unsigned* __restrict__ ctrl) {
  const int t = threadIdx.x;         // 0..255
  const int w = t >> 6;              // wave 0..3
  const int l = t & 63;              // lane owns o = 4l..4l+3
  const int loff = 4 * l;

  unsigned xcc;
  asm volatile("s_getreg_b32 %0, hwreg(HW_REG_XCC_ID)" : "=s"(xcc));
  xcc &= 7;

  __shared__ float borders[66];
  __shared__ int sgc[2];             // claimed {pgroup, chunk}
  __shared__ int jb[64];             // in-slab element base (i*65+j)*256
  __shared__ float4 w4[64];          // {w00, w01, w10, w11}

  borders_init(borders, t);
  if (t == 0) {
    int g = -1, c = -1;
    for (int q = 0; q < 8 && g < 0; ++q) {       // own XCD first, then steal
      int gg = ((int)xcc + q) & 7;
      unsigned cc = __hip_atomic_fetch_add(&ctrl[gg * 64], 1u,
                        __ATOMIC_RELAXED, __HIP_MEMORY_SCOPE_AGENT);
      if (cc < (unsigned)BARS) { g = gg; c = (int)cc; }
    }
    sgc[0] = g; sgc[1] = c;
  }
  __syncthreads();
  const int g = sgc[0], c = sgc[1];
  if (g < 0) return;                 // provably unreachable (512 claims/512 blocks)

  unsigned* phcnt = ctrl + 512 + g * 8 * 64;
  float acc[16][4] = {};

  slab_prefetch(fpt + (size_t)(8 * g) * SLAB_ELEMS, c, t);   // prologue: slab ph0

  for (int ph = 0; ph < 8; ++ph) {
    const int p = 8 * g + ph;
    const __half* slab = fpt + (size_t)p * SLAB_ELEMS;
    if (t < 64) {
      const int b = c * 64 + t;
      float x1 = x[(size_t)(2 * p) * NB + b]     * scale[2 * p]     + biasp[2 * p];
      float x2 = x[(size_t)(2 * p + 1) * NB + b] * scale[2 * p + 1] + biasp[2 * p + 1];
      const float lo = borders[0];
      const float hi = borders[64] - 1e-6f;
      x1 = fminf(fmaxf(x1, lo), hi);
      x2 = fminf(fmaxf(x2, lo), hi);
      int i = bsearch65(borders, x1);
      int j = bsearch65(borders, x2);
      float t1 = (x1 - borders[i]) / (borders[i + 1] - borders[i]);
      float t2 = (x2 - borders[j]) / (borders[j + 1] - borders[j]);
      jb[t] = (i * NG + j) * NO;
      w4[t] = make_float4((1.0f - t1) * (1.0f - t2),  // (i,   j)  : +0
                          (1.0f - t1) * t2,           // (i,   j+1): +NO
                          t1 * (1.0f - t2),           // (i+1, j)  : +NG*NO
                          t1 * t2);                   // (i+1, j+1): +NG*NO+NO
    }
    __syncthreads();
#pragma unroll
    for (int bb = 0; bb < 16; ++bb) {
      const int bl = w * 16 + bb;
      const float4 wv = w4[bl];
      const __half* q = slab + jb[bl] + loff;
      uint2 vA = *reinterpret_cast<const uint2*>(q);
      uint2 vB = *reinterpret_cast<const uint2*>(q + NO);
      uint2 vC = *reinterpret_cast<const uint2*>(q + NG * NO);
      uint2 vD = *reinterpret_cast<const uint2*>(q + NG * NO + NO);
      fma4h(acc[bb], wv.x, vA);
      fma4h(acc[bb], wv.y, vB);
      fma4h(acc[bb], wv.z, vC);
      fma4h(acc[bb], wv.w, vD);
    }
    if (ph < 7) {
      slab_prefetch(slab + SLAB_ELEMS, c, t);   // stream next slab into L2
      phase_wait(phcnt + ph * 64);              // keep pgroup on one slab
    }
  }

  // write partials: part[g][b][o], per-pgroup contiguous 4 MiB
#pragma unroll
  for (int bb = 0; bb < 16; ++bb) {
    const int b = c * 64 + w * 16 + bb;
    *reinterpret_cast<float4*>(&part[((size_t)g * NB + b) * NO + loff]) =
        make_float4(acc[bb][0], acc[bb][1], acc[bb][2], acc[bb][3]);
  }
}

// ---- K3: out = relu(W@x + bias) + wlm * sum_k part ----
__global__ __launch_bounds__(256) void lmkan_linear2(
    const float* __restrict__ x, const float* __restrict__ W,
    const float* __restrict__ bias_l, const int* __restrict__ relu_p,
    const float* __restrict__ wlm_p, const float* __restrict__ part,
    float* __restrict__ out) {
  const int b0 = blockIdx.x * 32;
  const int t = threadIdx.x;          // = output row o
  __shared__ __align__(16) float xs[32 * 132];

#pragma unroll
  for (int k = 0; k < 16; ++k) {
    int idx = t + 256 * k;
    int d = idx >> 5, bb = idx & 31;
    xs[bb * 132 + d] = x[(size_t)d * NB + b0 + bb];
  }
  __syncthreads();

  float acc[32];
#pragma unroll
  for (int bb = 0; bb < 32; ++bb) acc[bb] = 0.0f;

  const float4* W4 = reinterpret_cast<const float4*>(W + (size_t)t * ND);
#pragma unroll 8
  for (int d4 = 0; d4 < 32; ++d4) {
    float4 wv = W4[d4];
#pragma unroll
    for (int bb = 0; bb < 32; ++bb) {
      float4 xv = *reinterpret_cast<const float4*>(&xs[bb * 132 + d4 * 4]);
      acc[bb] = fmaf(wv.x, xv.x, acc[bb]);
      acc[bb] = fmaf(wv.y, xv.y, acc[bb]);
      acc[bb] = fmaf(wv.z, xv.z, acc[bb]);
      acc[bb] = fmaf(wv.w, xv.w, acc[bb]);
    }
  }

  const float bias = bias_l[t];
  const int rl = relu_p[0];
  const float wlm = wlm_p[0];
  float* orow = out + (size_t)t * NB + b0;
#pragma unroll 4
  for (int bb = 0; bb < 32; ++bb) {
    float lmsum = 0.0f;
    const float* pr = part + (size_t)(b0 + bb) * NO + t;  // lanes coalesced
#pragma unroll
    for (int k = 0; k < 8; ++k) lmsum += pr[(size_t)k * NB * NO];
    float v = acc[bb] + bias;
    if (rl) v = fmaxf(v, 0.0f);
    orow[bb] = v + wlm * lmsum;
  }
}

// ---- Fallback: direct fp32 gather, fused linear (exact, slow) ----
__global__ __launch_bounds__(64) void lmkan_gather_direct(
    const float* __restrict__ x, const float* __restrict__ scale,
    const float* __restrict__ biasp, const float* __restrict__ W,
    const float* __restrict__ bias_l, const float* __restrict__ wlm_p,
    const int* __restrict__ relu_p, const float* __restrict__ fp,
    float* __restrict__ out) {
  const int b = blockIdx.x;
  const int t = threadIdx.x;

  __shared__ float borders[66];
  __shared__ __align__(16) float xcol[ND];
  __shared__ int pbase[NP];
  __shared__ float4 pw[NP];

  for (int k = t; k < 65; k += 64) {
    float pk = fminf(fmaxf((float)k * (1.0f / 64.0f), 0.0078125f), 0.9921875f);
    borders[k] = 1.41421356237309515f * erfinvf(2.0f * pk - 1.0f);
  }
  xcol[t]      = x[(size_t)t * NB + b];
  xcol[t + 64] = x[(size_t)(t + 64) * NB + b];
  __syncthreads();

  {
    const int p = t;
    float x1 = xcol[2 * p]     * scale[2 * p]     + biasp[2 * p];
    float x2 = xcol[2 * p + 1] * scale[2 * p + 1] + biasp[2 * p + 1];
    const float lo = borders[0];
    const float hi = borders[64] - 1e-6f;
    x1 = fminf(fmaxf(x1, lo), hi);
    x2 = fminf(fmaxf(x2, lo), hi);
    int i = bsearch65(borders, x1);
    int j = bsearch65(borders, x2);
    float t1 = (x1 - borders[i]) / (borders[i + 1] - borders[i]);
    float t2 = (x2 - borders[j]) / (borders[j + 1] - borders[j]);
    pbase[p] = i * NG + j;
    pw[p] = make_float4((1.0f - t1) * (1.0f - t2), t1 * (1.0f - t2),
                        (1.0f - t1) * t2, t1 * t2);
  }
  __syncthreads();

  float acc[4] = {0, 0, 0, 0};
  for (int p = 0; p < NP; ++p) {
    int base = pbase[p];
    float4 wv = pw[p];
#pragma unroll
    for (int k = 0; k < 4; ++k) {
      size_t r = ((size_t)base * NO + (4 * t + k)) * NP + p;
      acc[k] += wv.x * fp[r] + wv.y * fp[r + 65 * PANEL] +
                wv.z * fp[r + PANEL] + wv.w * fp[r + 66 * PANEL];
    }
  }

  const float wlm = wlm_p[0];
  const int rl = relu_p[0];
  const float4* xc4 = reinterpret_cast<const float4*>(xcol);
#pragma unroll
  for (int k = 0; k < 4; ++k) {
    const int o = 4 * t + k;
    const float4* wr = reinterpret_cast<const float4*>(W + (size_t)o * ND);
    float s = 0.0f;
#pragma unroll 8
    for (int d4 = 0; d4 < ND / 4; ++d4) {
      float4 wv = wr[d4];
      float4 xv = xc4[d4];
      s = fmaf(wv.x, xv.x, s);
      s = fmaf(wv.y, xv.y, s);
      s = fmaf(wv.z, xv.z, s);
      s = fmaf(wv.w, xv.w, s);
    }
    s += bias_l[o];
    if (rl) s = fmaxf(s, 0.0f);
    out[(size_t)o * NB + b] = s + wlm * acc[k];
  }
}

extern "C" void kernel_launch(void* const* d_in, const int* in_sizes, int n_in,
                              void* d_out, int out_size, void* d_ws, size_t ws_size,
                              hipStream_t stream) {
  const float* x     = reinterpret_cast<const float*>(d_in[0]);
  const float* wlm   = reinterpret_cast<const float*>(d_in[1]);
  const int*   relu  = reinterpret_cast<const int*>(d_in[2]);
  const float* fp    = reinterpret_cast<const float*>(d_in[3]);
  const float* scale = reinterpret_cast<const float*>(d_in[4]);
  const float* biasp = reinterpret_cast<const float*>(d_in[5]);
  const float* W     = reinterpret_cast<const float*>(d_in[6]);
  const float* bl    = reinterpret_cast<const float*>(d_in[7]);
  float* out = reinterpret_cast<float*>(d_out);

  const size_t need = FPT_BYTES + PART_FLOATS * sizeof(float)
                      + CTRL_U32 * sizeof(unsigned);
  if (ws_size >= need) {
    char* base = reinterpret_cast<char*>(d_ws);
    __half* fpt = reinterpret_cast<__half*>(base);
    float* part = reinterpret_cast<float*>(base + FPT_BYTES);
    unsigned* ctrl = reinterpret_cast<unsigned*>(
        base + FPT_BYTES + PART_FLOATS * sizeof(float));
    lmkan_transpose4<<<NPANEL, 256, 0, stream>>>(fp, fpt, ctrl);
    lmkan_gather10<<<NBLK, 256, 0, stream>>>(x, scale, biasp, fpt, part, ctrl);
    lmkan_linear2<<<NB / 32, 256, 0, stream>>>(x, W, bl, relu, wlm, part, out);
  } else {
    lmkan_gather_direct<<<NB, 64, 0, stream>>>(x, scale, biasp, W, bl, wlm, relu, fp, out);
  }
}

// Round 11
// 184.665 us; speedup vs baseline: 1.3046x; 1.3046x over previous
//
#include <hip/hip_runtime.h>
#include <hip/hip_fp16.h>

// LMKAN_2D: out(O=256,B=4096) = relu(W(256x128)@x(128x4096) + bias_l)
//           + w_lm * sum_p bilinear4(fp[i,j,:,p])
// R11 = R5 structure (best: 182.4us) + slab layout enabling 1KB pair-loads.
// K1 transpose: fp[i][j][o][p] f32 -> fpt[p][i][j][o] f16 (132 MiB).
//    Loads 1KB/wave nt; LDS XOR-swizzled; stores 512B segments.
// K2 gather: block per b (256 thr = 4 waves x 16 p's). Per p: TWO 1KB
//    contiguous wave-reads (rows i and i+1; j/j+1 adjacent in-layout),
//    uint4/lane, lane-halves own j / j+1 column, depth-1 prefetch,
//    shfl_xor(32) merge + LDS merge. Half the load instrs/segments of R5.
// K3 linear: 128-block GEMM RMW-adds relu(Wx+b) into out.
// (R6-R10 phased-L2 arc abandoned: locality proven [FETCH 483->157MB] but
//  coordination cost always exceeded the L3->L2 gain.)

#define NB 4096
#define ND 128
#define NO 256
#define NP 64
#define NG 65
#define NPANEL 4225              // 65*65
#define PANEL 16384              // 256*64 elements per (i,j) src panel
#define SLAB_ELEMS ((size_t)NPANEL * NO)
#define FPT_ELEMS ((size_t)NP * SLAB_ELEMS)
#define FPT_BYTES (FPT_ELEMS * 2)    // 138,444,800 B

typedef float f32x4 __attribute__((ext_vector_type(4)));
union Pack8 { __half h[8]; uint4 v; };

__device__ __forceinline__ int bsearch65(const float* B, float v) {
  int lo = 0, hi = 65;
  while (lo < hi) {
    int m = (lo + hi) >> 1;
    if (B[m] <= v) lo = m + 1; else hi = m;
  }
  int i = lo - 1;
  return i < 0 ? 0 : (i > 63 ? 63 : i);
}

__device__ __forceinline__ void borders_init(float* borders, int t) {
  if (t < 65) {
    float pk = fminf(fmaxf((float)t * (1.0f / 64.0f), 0.0078125f), 0.9921875f);
    borders[t] = 1.41421356237309515f * erfinvf(2.0f * pk - 1.0f);
  }
}

// ---- K1: transpose fp[panel][o][p] f32 -> fpt[p][panel][o] f16 ----
__global__ __launch_bounds__(256) void lmkan_transpose4(
    const float* __restrict__ src, __half* __restrict__ dst) {
  const int panel = blockIdx.x;
  const int t = threadIdx.x;
  __shared__ __half lds[256 * 72];   // [o][72], p XOR-swizzled inside row

  const f32x4* s4 = reinterpret_cast<const f32x4*>(src + (size_t)panel * PANEL);
#pragma unroll
  for (int k = 0; k < 16; ++k) {
    int idx4 = t + 256 * k;          // 1KB contiguous per wave
    f32x4 v = __builtin_nontemporal_load(&s4[idx4]);  // read-once
    int o = idx4 >> 4;
    int p0 = (idx4 & 15) * 4;
    int p0s = p0 ^ (((o >> 3) & 15) << 2);
    union { __half2 h2[2]; uint2 u; } pk;
    pk.h2[0] = __floats2half2_rn(v[0], v[1]);
    pk.h2[1] = __floats2half2_rn(v[2], v[3]);
    *reinterpret_cast<uint2*>(&lds[o * 72 + p0s]) = pk.u;
  }
  __syncthreads();

  const int l = t & 63, w = t >> 6;
  const int o0 = (l & 31) * 8;
  const int swz = (l & 15) << 2;
#pragma unroll
  for (int ss = 0; ss < 8; ++ss) {
    int p = ss * 8 + w * 2 + (l >> 5);
    int prow = ((p & ~3) ^ swz) + (p & 3);
    Pack8 pk;
#pragma unroll
    for (int r = 0; r < 8; ++r) pk.h[r] = lds[(o0 + r) * 72 + prow];
    // slab-contiguous: row (p, panel)
    *reinterpret_cast<uint4*>(dst + ((size_t)p * NPANEL + panel) * NO + o0) = pk.v;
  }
}

__device__ __forceinline__ void fma8(float acc[8], float w, uint4 v) {
  const __half2* h = reinterpret_cast<const __half2*>(&v);
#pragma unroll
  for (int k = 0; k < 4; ++k) {
    float2 f = __half22float2(h[k]);
    acc[2 * k]     = fmaf(w, f.x, acc[2 * k]);
    acc[2 * k + 1] = fmaf(w, f.y, acc[2 * k + 1]);
  }
}

// ---- K2: gather, out = wlm * lmkan ----
__global__ __launch_bounds__(256) void lmkan_gather11(
    const float* __restrict__ x, const float* __restrict__ scale,
    const float* __restrict__ biasp, const float* __restrict__ wlm_p,
    const __half* __restrict__ fpt, float* __restrict__ out) {
  const int b = blockIdx.x;
  const int t = threadIdx.x;   // 0..255
  const int w = t >> 6;        // wave -> p in [16w, 16w+16)
  const int l = t & 63;
  const int side = l >> 5;     // 0: col j, 1: col j+1
  const int ol = l & 31;       // o-slot [8*ol, 8*ol+8)
  const int loff = 8 * l;      // = side*256 + 8*ol (halves into 1KB pair)

  __shared__ float borders[66];
  __shared__ float xcol[ND];
  __shared__ int jb[NP];           // element index of (p-slab, row(i,j), o=0)
  __shared__ float2 pws[2][NP];    // [side][p] = {w(row i), w(row i+1)}
  __shared__ __align__(16) float lm[4][NO];

  borders_init(borders, t);
  if (t < ND) xcol[t] = x[(size_t)t * NB + b];
  __syncthreads();

  if (t < NP) {
    const int p = t;
    float x1 = xcol[2 * p]     * scale[2 * p]     + biasp[2 * p];
    float x2 = xcol[2 * p + 1] * scale[2 * p + 1] + biasp[2 * p + 1];
    const float lo = borders[0];
    const float hi = borders[64] - 1e-6f;
    x1 = fminf(fmaxf(x1, lo), hi);
    x2 = fminf(fmaxf(x2, lo), hi);
    int i = bsearch65(borders, x1);
    int j = bsearch65(borders, x2);
    float t1 = (x1 - borders[i]) / (borders[i + 1] - borders[i]);
    float t2 = (x2 - borders[j]) / (borders[j + 1] - borders[j]);
    jb[p] = (p * NPANEL + i * NG + j) * NO;   // 69.2M max, fits int
    pws[0][p] = make_float2((1.0f - t1) * (1.0f - t2),  // (i,   j)
                            t1 * (1.0f - t2));          // (i+1, j)
    pws[1][p] = make_float2((1.0f - t1) * t2,           // (i,   j+1)
                            t1 * t2);                   // (i+1, j+1)
  }
  __syncthreads();

  float acc[8] = {0, 0, 0, 0, 0, 0, 0, 0};
  const int p0 = w * 16;

  // depth-1 software pipeline; per p: 2 x 1KB contiguous wave-reads
  const __half* q = fpt + jb[p0] + loff;
  uint4 v0 = *reinterpret_cast<const uint4*>(q);            // (i,   j+side)
  uint4 v1 = *reinterpret_cast<const uint4*>(q + NG * NO);  // (i+1, j+side)
#pragma unroll
  for (int pi = 0; pi < 16; ++pi) {
    const int p = p0 + pi;
    uint4 c0 = v0, c1 = v1;
    if (pi < 15) {
      const __half* qn = fpt + jb[p + 1] + loff;
      v0 = *reinterpret_cast<const uint4*>(qn);
      v1 = *reinterpret_cast<const uint4*>(qn + NG * NO);
    }
    const float2 wv = pws[side][p];
    fma8(acc, wv.x, c0);   // row i
    fma8(acc, wv.y, c1);   // row i+1
  }
  // merge j / j+1 lane-halves (shfl_xor 32 keeps ol, swaps side)
#pragma unroll
  for (int k = 0; k < 8; ++k) acc[k] += __shfl_xor(acc[k], 32, 64);
  if (l < 32) {
#pragma unroll
    for (int k = 0; k < 8; ++k) lm[w][8 * ol + k] = acc[k];
  }
  __syncthreads();

  const int o = t;
  out[(size_t)o * NB + b] =
      wlm_p[0] * (lm[0][o] + lm[1][o] + lm[2][o] + lm[3][o]);
}

// ---- K3: out += relu(W@x + bias) ----
__global__ __launch_bounds__(256) void lmkan_linear(
    const float* __restrict__ x, const float* __restrict__ W,
    const float* __restrict__ bias_l, const int* __restrict__ relu_p,
    float* __restrict__ out) {
  const int b0 = blockIdx.x * 32;
  const int t = threadIdx.x;          // = output row o
  __shared__ __align__(16) float xs[32 * 132];  // [bb][d], pad 132

#pragma unroll
  for (int k = 0; k < 16; ++k) {
    int idx = t + 256 * k;            // idx = d*32 + bb -> coalesced in b
    int d = idx >> 5, bb = idx & 31;
    xs[bb * 132 + d] = x[(size_t)d * NB + b0 + bb];
  }
  __syncthreads();

  float acc[32];
#pragma unroll
  for (int bb = 0; bb < 32; ++bb) acc[bb] = 0.0f;

  const float4* W4 = reinterpret_cast<const float4*>(W + (size_t)t * ND);
#pragma unroll 8
  for (int d4 = 0; d4 < 32; ++d4) {
    float4 wv = W4[d4];
#pragma unroll
    for (int bb = 0; bb < 32; ++bb) {
      float4 xv = *reinterpret_cast<const float4*>(&xs[bb * 132 + d4 * 4]);
      acc[bb] = fmaf(wv.x, xv.x, acc[bb]);
      acc[bb] = fmaf(wv.y, xv.y, acc[bb]);
      acc[bb] = fmaf(wv.z, xv.z, acc[bb]);
      acc[bb] = fmaf(wv.w, xv.w, acc[bb]);
    }
  }

  const float bias = bias_l[t];
  const int rl = relu_p[0];
  float* orow = out + (size_t)t * NB + b0;
#pragma unroll
  for (int bb = 0; bb < 32; ++bb) {
    float v = acc[bb] + bias;
    if (rl) v = fmaxf(v, 0.0f);
    orow[bb] += v;   // RMW: gather already wrote wlm*lmkan
  }
}

// ---- Fallback: direct fp32 gather, fused linear (exact, slow) ----
__global__ __launch_bounds__(64) void lmkan_gather_direct(
    const float* __restrict__ x, const float* __restrict__ scale,
    const float* __restrict__ biasp, const float* __restrict__ W,
    const float* __restrict__ bias_l, const float* __restrict__ wlm_p,
    const int* __restrict__ relu_p, const float* __restrict__ fp,
    float* __restrict__ out) {
  const int b = blockIdx.x;
  const int t = threadIdx.x;

  __shared__ float borders[66];
  __shared__ __align__(16) float xcol[ND];
  __shared__ int pbase[NP];
  __shared__ float4 pw[NP];

  for (int k = t; k < 65; k += 64) {
    float pk = fminf(fmaxf((float)k * (1.0f / 64.0f), 0.0078125f), 0.9921875f);
    borders[k] = 1.41421356237309515f * erfinvf(2.0f * pk - 1.0f);
  }
  xcol[t]      = x[(size_t)t * NB + b];
  xcol[t + 64] = x[(size_t)(t + 64) * NB + b];
  __syncthreads();

  {
    const int p = t;
    float x1 = xcol[2 * p]     * scale[2 * p]     + biasp[2 * p];
    float x2 = xcol[2 * p + 1] * scale[2 * p + 1] + biasp[2 * p + 1];
    const float lo = borders[0];
    const float hi = borders[64] - 1e-6f;
    x1 = fminf(fmaxf(x1, lo), hi);
    x2 = fminf(fmaxf(x2, lo), hi);
    int i = bsearch65(borders, x1);
    int j = bsearch65(borders, x2);
    float t1 = (x1 - borders[i]) / (borders[i + 1] - borders[i]);
    float t2 = (x2 - borders[j]) / (borders[j + 1] - borders[j]);
    pbase[p] = i * NG + j;
    pw[p] = make_float4((1.0f - t1) * (1.0f - t2), t1 * (1.0f - t2),
                        (1.0f - t1) * t2, t1 * t2);
  }
  __syncthreads();

  float acc[4] = {0, 0, 0, 0};
  for (int p = 0; p < NP; ++p) {
    int base = pbase[p];
    float4 wv = pw[p];
#pragma unroll
    for (int k = 0; k < 4; ++k) {
      size_t r = ((size_t)base * NO + (4 * t + k)) * NP + p;
      acc[k] += wv.x * fp[r] + wv.y * fp[r + 65 * PANEL] +
                wv.z * fp[r + PANEL] + wv.w * fp[r + 66 * PANEL];
    }
  }

  const float wlm = wlm_p[0];
  const int rl = relu_p[0];
  const float4* xc4 = reinterpret_cast<const float4*>(xcol);
#pragma unroll
  for (int k = 0; k < 4; ++k) {
    const int o = 4 * t + k;
    const float4* wr = reinterpret_cast<const float4*>(W + (size_t)o * ND);
    float s = 0.0f;
#pragma unroll 8
    for (int d4 = 0; d4 < ND / 4; ++d4) {
      float4 wv = wr[d4];
      float4 xv = xc4[d4];
      s = fmaf(wv.x, xv.x, s);
      s = fmaf(wv.y, xv.y, s);
      s = fmaf(wv.z, xv.z, s);
      s = fmaf(wv.w, xv.w, s);
    }
    s += bias_l[o];
    if (rl) s = fmaxf(s, 0.0f);
    out[(size_t)o * NB + b] = s + wlm * acc[k];
  }
}

extern "C" void kernel_launch(void* const* d_in, const int* in_sizes, int n_in,
                              void* d_out, int out_size, void* d_ws, size_t ws_size,
                              hipStream_t stream) {
  const float* x     = reinterpret_cast<const float*>(d_in[0]);
  const float* wlm   = reinterpret_cast<const float*>(d_in[1]);
  const int*   relu  = reinterpret_cast<const int*>(d_in[2]);
  const float* fp    = reinterpret_cast<const float*>(d_in[3]);
  const float* scale = reinterpret_cast<const float*>(d_in[4]);
  const float* biasp = reinterpret_cast<const float*>(d_in[5]);
  const float* W     = reinterpret_cast<const float*>(d_in[6]);
  const float* bl    = reinterpret_cast<const float*>(d_in[7]);
  float* out = reinterpret_cast<float*>(d_out);

  if (ws_size >= FPT_BYTES) {
    __half* fpt = reinterpret_cast<__half*>(d_ws);
    lmkan_transpose4<<<NPANEL, 256, 0, stream>>>(fp, fpt);
    lmkan_gather11<<<NB, 256, 0, stream>>>(x, scale, biasp, wlm, fpt, out);
    lmkan_linear<<<NB / 32, 256, 0, stream>>>(x, W, bl, relu, out);
  } else {
    lmkan_gather_direct<<<NB, 64, 0, stream>>>(x, scale, biasp, W, bl, wlm, relu, fp, out);
  }
}